// Round 7
// baseline (654.710 us; speedup 1.0000x reference)
//
#include <hip/hip_runtime.h>
#include <math.h>

#define BSZ 8192
#define DDIM 512
#define EMA_C 0.99
// acc is computed directly in logit scale: each side scaled by 8/||x|| so
// acc = 64*cos. 8 is an exact power of two -> scaling is lossless in fp16/fp32.
#define SC 64.0f
#define NFINAL 32

typedef _Float16 f16;
typedef _Float16 half8 __attribute__((ext_vector_type(8)));
typedef float f32x4 __attribute__((ext_vector_type(4)));

__device__ __forceinline__ void gload16(const void* g, void* l) {
    __builtin_amdgcn_global_load_lds(
        (const __attribute__((address_space(1))) void*)g,
        (__attribute__((address_space(3))) void*)l, 16, 0, 0);
}

// Normalize rows, scale by 8/||x||, split into fp16 hi + lo, store row-major.
// Also zeroes the stats region (pos/neg/Tsum/lossAcc/ticket) — ws is 0xAA-poisoned.
__global__ void prep_kernel(const float* __restrict__ f1,
                            const float* __restrict__ f2,
                            f16* __restrict__ Ah, f16* __restrict__ Al,
                            f16* __restrict__ Bh, f16* __restrict__ Bl,
                            float* __restrict__ stats) {
    if (blockIdx.y == 0 && blockIdx.x < 25) {
        int idx = blockIdx.x * 256 + threadIdx.x;
        if (idx < (3 * BSZ + 4) / 4)
            reinterpret_cast<float4*>(stats)[idx] = make_float4(0.f, 0.f, 0.f, 0.f);
    }
    const int w = threadIdx.x >> 6, l = threadIdx.x & 63;
    const int row = blockIdx.x * 4 + w;
    const float* src = (blockIdx.y == 0) ? f1 : f2;
    f16* dh = (blockIdx.y == 0) ? Ah : Bh;
    f16* dl = (blockIdx.y == 0) ? Al : Bl;
    const float4* p = reinterpret_cast<const float4*>(src + (size_t)row * DDIM);
    float4 v0 = p[l * 2], v1 = p[l * 2 + 1];
    float s = v0.x * v0.x + v0.y * v0.y + v0.z * v0.z + v0.w * v0.w +
              v1.x * v1.x + v1.y * v1.y + v1.z * v1.z + v1.w * v1.w;
#pragma unroll
    for (int off = 32; off; off >>= 1) s += __shfl_xor(s, off);
    const float g = 8.0f / sqrtf(s);
    float x[8] = {v0.x, v0.y, v0.z, v0.w, v1.x, v1.y, v1.z, v1.w};
    half8 h8, l8;
#pragma unroll
    for (int e = 0; e < 8; ++e) {
        float xs = x[e] * g;
        f16 hi = (f16)xs;
        h8[e] = hi;
        l8[e] = (f16)(xs - (float)hi);
    }
    *reinterpret_cast<half8*>(dh + (size_t)row * DDIM + l * 8) = h8;
    *reinterpret_cast<half8*>(dl + (size_t)row * DDIM + l * 8) = l8;
}

// Block tile 128(M) x 256(N), 4 waves (2x2) of 64x128, MFMA 16x16x32 f16.
// 3-term hi/lo GEMM, single-buffered LDS, compiler-scheduled (R3 structure —
// proven 217us / 44% MfmaUtil). launch_bounds(256,3): 48KB LDS x3 = 144KB/CU,
// 116 VGPR x3 waves/SIMD fits -> 3 blocks/CU for cross-block overlap (m114).
__launch_bounds__(256, 3)
__global__ void gemm_pass_kernel(const f16* __restrict__ Ah, const f16* __restrict__ Al,
                                 const f16* __restrict__ Bh, const f16* __restrict__ Bl,
                                 const int* __restrict__ label,
                                 float* __restrict__ pos,
                                 float* __restrict__ negv,
                                 float* __restrict__ Tsum) {
    // LDS: Ah[128][32], Al, Bh[256][32], Bl  (halfs; 64-B rows, slot-swizzled)
    __shared__ __align__(16) char LDS[49152];
    char* AhL = LDS;
    char* AlL = LDS + 8192;
    char* BhL = LDS + 16384;
    char* BlL = LDS + 32768;

    const int t = threadIdx.x, w = t >> 6, l = t & 63;
    const int rowBase = blockIdx.y * 128;
    const int colBase = blockIdx.x * 256;

    // ---- staging source addressing (pre-swizzled so LDS dest is linear) ----
    // LDS slot (row, s) holds k-group kg = s ^ ((row>>1)&3).
    // gload dest = base + lane*16 -> row = 16q + (lane>>2), s = lane&3
    //   -> kg = (lane&3) ^ ((lane>>3)&3)
    const int kg = (l & 3) ^ ((l >> 3) & 3);
    const int rsub = l >> 2;  // 0..15

    const int qA0 = 2 * w, qA1 = 2 * w + 1;
    const int qB0 = 4 * w, qB1 = 4 * w + 1, qB2 = 4 * w + 2, qB3 = 4 * w + 3;

    const f16* pAh0 = Ah + (size_t)(rowBase + 16 * qA0 + rsub) * DDIM + kg * 8;
    const f16* pAh1 = Ah + (size_t)(rowBase + 16 * qA1 + rsub) * DDIM + kg * 8;
    const f16* pAl0 = Al + (size_t)(rowBase + 16 * qA0 + rsub) * DDIM + kg * 8;
    const f16* pAl1 = Al + (size_t)(rowBase + 16 * qA1 + rsub) * DDIM + kg * 8;
    const f16* pBh0 = Bh + (size_t)(colBase + 16 * qB0 + rsub) * DDIM + kg * 8;
    const f16* pBh1 = Bh + (size_t)(colBase + 16 * qB1 + rsub) * DDIM + kg * 8;
    const f16* pBh2 = Bh + (size_t)(colBase + 16 * qB2 + rsub) * DDIM + kg * 8;
    const f16* pBh3 = Bh + (size_t)(colBase + 16 * qB3 + rsub) * DDIM + kg * 8;
    const f16* pBl0 = Bl + (size_t)(colBase + 16 * qB0 + rsub) * DDIM + kg * 8;
    const f16* pBl1 = Bl + (size_t)(colBase + 16 * qB1 + rsub) * DDIM + kg * 8;
    const f16* pBl2 = Bl + (size_t)(colBase + 16 * qB2 + rsub) * DDIM + kg * 8;
    const f16* pBl3 = Bl + (size_t)(colBase + 16 * qB3 + rsub) * DDIM + kg * 8;

    char* dAh0 = AhL + qA0 * 1024;
    char* dAh1 = AhL + qA1 * 1024;
    char* dAl0 = AlL + qA0 * 1024;
    char* dAl1 = AlL + qA1 * 1024;
    char* dBh0 = BhL + qB0 * 1024;
    char* dBh1 = BhL + qB1 * 1024;
    char* dBh2 = BhL + qB2 * 1024;
    char* dBh3 = BhL + qB3 * 1024;
    char* dBl0 = BlL + qB0 * 1024;
    char* dBl1 = BlL + qB1 * 1024;
    char* dBl2 = BlL + qB2 * 1024;
    char* dBl3 = BlL + qB3 * 1024;

    // ---- fragment read addressing ----
    const int wrow = w >> 1, wcol = w & 1;
    const int ar = l & 15;
    const int ssw = (l >> 4) ^ ((l >> 1) & 3);

    f32x4 acc[4][8];
#pragma unroll
    for (int rt = 0; rt < 4; ++rt)
#pragma unroll
        for (int ct = 0; ct < 8; ++ct) acc[rt][ct] = (f32x4){0.f, 0.f, 0.f, 0.f};

    for (int k0 = 0; k0 < DDIM; k0 += 32) {
        __syncthreads();
        gload16(pAh0 + k0, dAh0);
        gload16(pAh1 + k0, dAh1);
        gload16(pAl0 + k0, dAl0);
        gload16(pAl1 + k0, dAl1);
        gload16(pBh0 + k0, dBh0);
        gload16(pBh1 + k0, dBh1);
        gload16(pBh2 + k0, dBh2);
        gload16(pBh3 + k0, dBh3);
        gload16(pBl0 + k0, dBl0);
        gload16(pBl1 + k0, dBl1);
        gload16(pBl2 + k0, dBl2);
        gload16(pBl3 + k0, dBl3);
        __syncthreads();

        half8 ahf[4], alf[4];
#pragma unroll
        for (int rt = 0; rt < 4; ++rt) {
            const int off = (wrow * 64 + rt * 16 + ar) * 64 + ssw * 16;
            ahf[rt] = *reinterpret_cast<const half8*>(AhL + off);
            alf[rt] = *reinterpret_cast<const half8*>(AlL + off);
        }
#pragma unroll
        for (int ct = 0; ct < 8; ++ct) {
            const int off = (wcol * 128 + ct * 16 + ar) * 64 + ssw * 16;
            half8 bh = *reinterpret_cast<const half8*>(BhL + off);
            half8 bl = *reinterpret_cast<const half8*>(BlL + off);
#pragma unroll
            for (int rt = 0; rt < 4; ++rt) {
                acc[rt][ct] = __builtin_amdgcn_mfma_f32_16x16x32_f16(ahf[rt], bh, acc[rt][ct], 0, 0, 0);
                acc[rt][ct] = __builtin_amdgcn_mfma_f32_16x16x32_f16(ahf[rt], bl, acc[rt][ct], 0, 0, 0);
                acc[rt][ct] = __builtin_amdgcn_mfma_f32_16x16x32_f16(alf[rt], bh, acc[rt][ct], 0, 0, 0);
            }
        }
    }

    // ---- epilogue: clip, mask, exp, per-row sum/max ----
    // C/D: col = lane&15, row = (lane>>4)*4 + reg  [m89-verified layout]
    const int rowB2 = rowBase + wrow * 64;
    const int colB2 = colBase + wcol * 128;
    const int cl = l & 15, h = l >> 4;

    int lcs[8];
#pragma unroll
    for (int ct = 0; ct < 8; ++ct) lcs[ct] = label[colB2 + ct * 16 + cl];

    float psum[4][4], pmax[4][4];
#pragma unroll
    for (int rt = 0; rt < 4; ++rt)
#pragma unroll
        for (int reg = 0; reg < 4; ++reg) { psum[rt][reg] = 0.f; pmax[rt][reg] = 0.f; }

#pragma unroll
    for (int rt = 0; rt < 4; ++rt) {
        int lr[4];
#pragma unroll
        for (int reg = 0; reg < 4; ++reg) lr[reg] = label[rowB2 + rt * 16 + h * 4 + reg];
#pragma unroll
        for (int ct = 0; ct < 8; ++ct) {
            const int gcol = colB2 + ct * 16 + cl;
#pragma unroll
            for (int reg = 0; reg < 4; ++reg) {
                float v = acc[rt][ct][reg];
                v = fminf(fmaxf(v, -SC), SC);  // clip in logit units (+-64)
                const int grow = rowB2 + rt * 16 + h * 4 + reg;
                if (grow == gcol) {
                    pos[grow] = v;  // scaled diag; exactly one writer chip-wide
                } else {
                    if (lr[reg] == lcs[ct]) v = 0.0f;  // same-label mask
                    psum[rt][reg] += __expf(v);        // e^(64*cos)
                    pmax[rt][reg] = fmaxf(pmax[rt][reg], v);
                }
            }
        }
    }

#pragma unroll
    for (int rt = 0; rt < 4; ++rt)
#pragma unroll
        for (int reg = 0; reg < 4; ++reg) {
            float s = psum[rt][reg], mx = pmax[rt][reg];
#pragma unroll
            for (int m = 1; m <= 8; m <<= 1) {
                s += __shfl_xor(s, m);
                mx = fmaxf(mx, __shfl_xor(mx, m));
            }
            if (cl == 0) {
                const int grow = rowB2 + rt * 16 + h * 4 + reg;
                atomicAdd(&Tsum[grow], s);
                // values >= 0 -> int compare == float compare; init bits 0.0f
                atomicMax(reinterpret_cast<int*>(&negv[grow]), __float_as_int(mx));
            }
        }
}

// 32 blocks x 256 threads: each thread owns exactly one row. Every block
// redundantly computes the (bit-identical) m-sum; per-row loss in double;
// block partial -> f64 atomicAdd; last block (ticket) writes out.
__global__ void final_kernel(const float* __restrict__ pos,
                             const float* __restrict__ negv,
                             const float* __restrict__ Tsum,
                             double* __restrict__ lossAcc,
                             int* __restrict__ ticket,
                             float* __restrict__ out) {
    __shared__ double sd[256];
    const int t = threadIdx.x;

    // ---- mLogit = SC*m = EMA * sum(pos-neg)/B ----
    double s = 0.0;
    for (int i = t; i < BSZ; i += 256) s += (double)pos[i] - (double)negv[i];
    sd[t] = s;
    __syncthreads();
    for (int off = 128; off; off >>= 1) {
        if (t < off) sd[t] += sd[t + off];
        __syncthreads();
    }
    const double mLogit = EMA_C * sd[0] / BSZ;
    __syncthreads();

    // ---- one row per thread: loss = log(T + exp(d)) - d, stable ----
    const int row = blockIdx.x * 256 + t;  // NFINAL*256 == BSZ
    double d  = (double)pos[row] - mLogit;
    double lt = log((double)Tsum[row]);
    double l;
    if (d >= lt) l = log1p(exp(lt - d));
    else         l = (lt - d) + log1p(exp(d - lt));
    sd[t] = l;
    __syncthreads();
    for (int off = 128; off; off >>= 1) {
        if (t < off) sd[t] += sd[t + off];
        __syncthreads();
    }
    if (t == 0) {
        atomicAdd(lossAcc, sd[0]);
        __threadfence();
        int done = atomicAdd(ticket, 1);
        if (done == NFINAL - 1) {
            double total = atomicAdd(lossAcc, 0.0);  // RMW read: coherent total
            out[0] = (float)(total / BSZ);
        }
    }
}

extern "C" void kernel_launch(void* const* d_in, const int* in_sizes, int n_in,
                              void* d_out, int out_size, void* d_ws, size_t ws_size,
                              hipStream_t stream) {
    const float* f1    = (const float*)d_in[0];
    const float* f2    = (const float*)d_in[1];
    const int*   label = (const int*)d_in[2];
    float* out = (float*)d_out;

    // ws layout: pos[B], neg[B], Tsum[B] (f32), lossAcc (f64), ticket (i32),
    // pad to 16B, then Ah/Al/Bh/Bl fp16 matrices.
    float* stats = (float*)d_ws;
    float* pos   = stats;
    float* neg   = stats + BSZ;
    float* Tsum  = stats + 2 * BSZ;
    double* lossAcc = (double*)(stats + 3 * BSZ);       // byte 98304, 8-aligned
    int* ticket  = (int*)(stats + 3 * BSZ + 2);
    f16* Ah = (f16*)((char*)d_ws + 3 * BSZ * sizeof(float) + 16);
    f16* Al = Ah + (size_t)BSZ * DDIM;
    f16* Bh = Al + (size_t)BSZ * DDIM;
    f16* Bl = Bh + (size_t)BSZ * DDIM;

    prep_kernel<<<dim3(BSZ / 4, 2), dim3(256), 0, stream>>>(f1, f2, Ah, Al, Bh, Bl, stats);

    gemm_pass_kernel<<<dim3(BSZ / 256, BSZ / 128), dim3(256), 0, stream>>>(
        Ah, Al, Bh, Bl, label, pos, neg, Tsum);

    final_kernel<<<dim3(NFINAL), dim3(256), 0, stream>>>(pos, neg, Tsum, lossAcc, ticket, out);
}

// Round 8
// 319.454 us; speedup vs baseline: 2.0495x; 2.0495x over previous
//
#include <hip/hip_runtime.h>
#include <math.h>

#define BSZ 8192
#define DDIM 512
#define EMA_C 0.99
// acc is computed directly in logit scale: each side scaled by 8/||x|| so
// acc = 64*cos. 8 is an exact power of two -> scaling is lossless in fp16/fp32.
#define SC 64.0f
#define NFINAL 32

typedef _Float16 f16;
typedef _Float16 half8 __attribute__((ext_vector_type(8)));
typedef float f32x4 __attribute__((ext_vector_type(4)));

__device__ __forceinline__ void gload16(const void* g, void* l) {
    __builtin_amdgcn_global_load_lds(
        (const __attribute__((address_space(1))) void*)g,
        (__attribute__((address_space(3))) void*)l, 16, 0, 0);
}

// Normalize rows, scale by 8/||x||, split into fp16 hi + lo, store row-major.
// Also zeroes the stats region (pos/neg/Tsum/lossAcc/ticket) — ws is 0xAA-poisoned.
__global__ void prep_kernel(const float* __restrict__ f1,
                            const float* __restrict__ f2,
                            f16* __restrict__ Ah, f16* __restrict__ Al,
                            f16* __restrict__ Bh, f16* __restrict__ Bl,
                            float* __restrict__ stats) {
    if (blockIdx.y == 0 && blockIdx.x < 25) {
        int idx = blockIdx.x * 256 + threadIdx.x;
        if (idx < (3 * BSZ + 4) / 4)
            reinterpret_cast<float4*>(stats)[idx] = make_float4(0.f, 0.f, 0.f, 0.f);
    }
    const int w = threadIdx.x >> 6, l = threadIdx.x & 63;
    const int row = blockIdx.x * 4 + w;
    const float* src = (blockIdx.y == 0) ? f1 : f2;
    f16* dh = (blockIdx.y == 0) ? Ah : Bh;
    f16* dl = (blockIdx.y == 0) ? Al : Bl;
    const float4* p = reinterpret_cast<const float4*>(src + (size_t)row * DDIM);
    float4 v0 = p[l * 2], v1 = p[l * 2 + 1];
    float s = v0.x * v0.x + v0.y * v0.y + v0.z * v0.z + v0.w * v0.w +
              v1.x * v1.x + v1.y * v1.y + v1.z * v1.z + v1.w * v1.w;
#pragma unroll
    for (int off = 32; off; off >>= 1) s += __shfl_xor(s, off);
    const float g = 8.0f / sqrtf(s);
    float x[8] = {v0.x, v0.y, v0.z, v0.w, v1.x, v1.y, v1.z, v1.w};
    half8 h8, l8;
#pragma unroll
    for (int e = 0; e < 8; ++e) {
        float xs = x[e] * g;
        f16 hi = (f16)xs;
        h8[e] = hi;
        l8[e] = (f16)(xs - (float)hi);
    }
    *reinterpret_cast<half8*>(dh + (size_t)row * DDIM + l * 8) = h8;
    *reinterpret_cast<half8*>(dl + (size_t)row * DDIM + l * 8) = l8;
}

// Block tile 128(M) x 256(N), 4 waves (2x2) of 64x128, MFMA 16x16x32 f16.
// 3-term hi/lo GEMM, single-buffered LDS, compiler-scheduled. R3/R4-proven:
// lb(256,2) -> 2 blocks/CU (96KB LDS, no register spill; 116 VGPR + 64 AGPR).
// Cross-block implicit overlap (m114) covers the staging-barrier drain.
// NOTE: lb(256,3) forces the acc to spill (R7: VGPR 84, FETCH 8x, 600us).
__launch_bounds__(256, 2)
__global__ void gemm_pass_kernel(const f16* __restrict__ Ah, const f16* __restrict__ Al,
                                 const f16* __restrict__ Bh, const f16* __restrict__ Bl,
                                 const int* __restrict__ label,
                                 float* __restrict__ pos,
                                 float* __restrict__ negv,
                                 float* __restrict__ Tsum) {
    // LDS: Ah[128][32], Al, Bh[256][32], Bl  (halfs; 64-B rows, slot-swizzled)
    __shared__ __align__(16) char LDS[49152];
    char* AhL = LDS;
    char* AlL = LDS + 8192;
    char* BhL = LDS + 16384;
    char* BlL = LDS + 32768;

    const int t = threadIdx.x, w = t >> 6, l = t & 63;
    const int rowBase = blockIdx.y * 128;
    const int colBase = blockIdx.x * 256;

    // ---- staging source addressing (pre-swizzled so LDS dest is linear) ----
    // LDS slot (row, s) holds k-group kg = s ^ ((row>>1)&3).
    // gload dest = base + lane*16 -> row = 16q + (lane>>2), s = lane&3
    //   -> kg = (lane&3) ^ ((lane>>3)&3)
    const int kg = (l & 3) ^ ((l >> 3) & 3);
    const int rsub = l >> 2;  // 0..15

    const int qA0 = 2 * w, qA1 = 2 * w + 1;
    const int qB0 = 4 * w, qB1 = 4 * w + 1, qB2 = 4 * w + 2, qB3 = 4 * w + 3;

    const f16* pAh0 = Ah + (size_t)(rowBase + 16 * qA0 + rsub) * DDIM + kg * 8;
    const f16* pAh1 = Ah + (size_t)(rowBase + 16 * qA1 + rsub) * DDIM + kg * 8;
    const f16* pAl0 = Al + (size_t)(rowBase + 16 * qA0 + rsub) * DDIM + kg * 8;
    const f16* pAl1 = Al + (size_t)(rowBase + 16 * qA1 + rsub) * DDIM + kg * 8;
    const f16* pBh0 = Bh + (size_t)(colBase + 16 * qB0 + rsub) * DDIM + kg * 8;
    const f16* pBh1 = Bh + (size_t)(colBase + 16 * qB1 + rsub) * DDIM + kg * 8;
    const f16* pBh2 = Bh + (size_t)(colBase + 16 * qB2 + rsub) * DDIM + kg * 8;
    const f16* pBh3 = Bh + (size_t)(colBase + 16 * qB3 + rsub) * DDIM + kg * 8;
    const f16* pBl0 = Bl + (size_t)(colBase + 16 * qB0 + rsub) * DDIM + kg * 8;
    const f16* pBl1 = Bl + (size_t)(colBase + 16 * qB1 + rsub) * DDIM + kg * 8;
    const f16* pBl2 = Bl + (size_t)(colBase + 16 * qB2 + rsub) * DDIM + kg * 8;
    const f16* pBl3 = Bl + (size_t)(colBase + 16 * qB3 + rsub) * DDIM + kg * 8;

    char* dAh0 = AhL + qA0 * 1024;
    char* dAh1 = AhL + qA1 * 1024;
    char* dAl0 = AlL + qA0 * 1024;
    char* dAl1 = AlL + qA1 * 1024;
    char* dBh0 = BhL + qB0 * 1024;
    char* dBh1 = BhL + qB1 * 1024;
    char* dBh2 = BhL + qB2 * 1024;
    char* dBh3 = BhL + qB3 * 1024;
    char* dBl0 = BlL + qB0 * 1024;
    char* dBl1 = BlL + qB1 * 1024;
    char* dBl2 = BlL + qB2 * 1024;
    char* dBl3 = BlL + qB3 * 1024;

    // ---- fragment read addressing ----
    const int wrow = w >> 1, wcol = w & 1;
    const int ar = l & 15;
    const int ssw = (l >> 4) ^ ((l >> 1) & 3);

    f32x4 acc[4][8];
#pragma unroll
    for (int rt = 0; rt < 4; ++rt)
#pragma unroll
        for (int ct = 0; ct < 8; ++ct) acc[rt][ct] = (f32x4){0.f, 0.f, 0.f, 0.f};

    for (int k0 = 0; k0 < DDIM; k0 += 32) {
        __syncthreads();
        gload16(pAh0 + k0, dAh0);
        gload16(pAh1 + k0, dAh1);
        gload16(pAl0 + k0, dAl0);
        gload16(pAl1 + k0, dAl1);
        gload16(pBh0 + k0, dBh0);
        gload16(pBh1 + k0, dBh1);
        gload16(pBh2 + k0, dBh2);
        gload16(pBh3 + k0, dBh3);
        gload16(pBl0 + k0, dBl0);
        gload16(pBl1 + k0, dBl1);
        gload16(pBl2 + k0, dBl2);
        gload16(pBl3 + k0, dBl3);
        __syncthreads();

        half8 ahf[4], alf[4];
#pragma unroll
        for (int rt = 0; rt < 4; ++rt) {
            const int off = (wrow * 64 + rt * 16 + ar) * 64 + ssw * 16;
            ahf[rt] = *reinterpret_cast<const half8*>(AhL + off);
            alf[rt] = *reinterpret_cast<const half8*>(AlL + off);
        }
#pragma unroll
        for (int ct = 0; ct < 8; ++ct) {
            const int off = (wcol * 128 + ct * 16 + ar) * 64 + ssw * 16;
            half8 bh = *reinterpret_cast<const half8*>(BhL + off);
            half8 bl = *reinterpret_cast<const half8*>(BlL + off);
#pragma unroll
            for (int rt = 0; rt < 4; ++rt) {
                acc[rt][ct] = __builtin_amdgcn_mfma_f32_16x16x32_f16(ahf[rt], bh, acc[rt][ct], 0, 0, 0);
                acc[rt][ct] = __builtin_amdgcn_mfma_f32_16x16x32_f16(ahf[rt], bl, acc[rt][ct], 0, 0, 0);
                acc[rt][ct] = __builtin_amdgcn_mfma_f32_16x16x32_f16(alf[rt], bh, acc[rt][ct], 0, 0, 0);
            }
        }
    }

    // ---- epilogue: clip, mask, exp, per-row sum/max ----
    // C/D: col = lane&15, row = (lane>>4)*4 + reg  [m89-verified layout]
    const int rowB2 = rowBase + wrow * 64;
    const int colB2 = colBase + wcol * 128;
    const int cl = l & 15, h = l >> 4;

    int lcs[8];
#pragma unroll
    for (int ct = 0; ct < 8; ++ct) lcs[ct] = label[colB2 + ct * 16 + cl];

    float psum[4][4], pmax[4][4];
#pragma unroll
    for (int rt = 0; rt < 4; ++rt)
#pragma unroll
        for (int reg = 0; reg < 4; ++reg) { psum[rt][reg] = 0.f; pmax[rt][reg] = 0.f; }

#pragma unroll
    for (int rt = 0; rt < 4; ++rt) {
        int lr[4];
#pragma unroll
        for (int reg = 0; reg < 4; ++reg) lr[reg] = label[rowB2 + rt * 16 + h * 4 + reg];
#pragma unroll
        for (int ct = 0; ct < 8; ++ct) {
            const int gcol = colB2 + ct * 16 + cl;
#pragma unroll
            for (int reg = 0; reg < 4; ++reg) {
                float v = acc[rt][ct][reg];
                v = fminf(fmaxf(v, -SC), SC);  // clip in logit units (+-64)
                const int grow = rowB2 + rt * 16 + h * 4 + reg;
                if (grow == gcol) {
                    pos[grow] = v;  // scaled diag; exactly one writer chip-wide
                } else {
                    if (lr[reg] == lcs[ct]) v = 0.0f;  // same-label mask
                    psum[rt][reg] += __expf(v);        // e^(64*cos)
                    pmax[rt][reg] = fmaxf(pmax[rt][reg], v);
                }
            }
        }
    }

#pragma unroll
    for (int rt = 0; rt < 4; ++rt)
#pragma unroll
        for (int reg = 0; reg < 4; ++reg) {
            float s = psum[rt][reg], mx = pmax[rt][reg];
#pragma unroll
            for (int m = 1; m <= 8; m <<= 1) {
                s += __shfl_xor(s, m);
                mx = fmaxf(mx, __shfl_xor(mx, m));
            }
            if (cl == 0) {
                const int grow = rowB2 + rt * 16 + h * 4 + reg;
                atomicAdd(&Tsum[grow], s);
                // values >= 0 -> int compare == float compare; init bits 0.0f
                atomicMax(reinterpret_cast<int*>(&negv[grow]), __float_as_int(mx));
            }
        }
}

// 32 blocks x 256 threads: each thread owns exactly one row. Every block
// redundantly computes the (bit-identical) m-sum; per-row loss in double;
// block partial -> f64 atomicAdd; last block (ticket) writes out.
__global__ void final_kernel(const float* __restrict__ pos,
                             const float* __restrict__ negv,
                             const float* __restrict__ Tsum,
                             double* __restrict__ lossAcc,
                             int* __restrict__ ticket,
                             float* __restrict__ out) {
    __shared__ double sd[256];
    const int t = threadIdx.x;

    // ---- mLogit = SC*m = EMA * sum(pos-neg)/B ----
    double s = 0.0;
    for (int i = t; i < BSZ; i += 256) s += (double)pos[i] - (double)negv[i];
    sd[t] = s;
    __syncthreads();
    for (int off = 128; off; off >>= 1) {
        if (t < off) sd[t] += sd[t + off];
        __syncthreads();
    }
    const double mLogit = EMA_C * sd[0] / BSZ;
    __syncthreads();

    // ---- one row per thread: loss = log(T + exp(d)) - d, stable ----
    const int row = blockIdx.x * 256 + t;  // NFINAL*256 == BSZ
    double d  = (double)pos[row] - mLogit;
    double lt = log((double)Tsum[row]);
    double l;
    if (d >= lt) l = log1p(exp(lt - d));
    else         l = (lt - d) + log1p(exp(d - lt));
    sd[t] = l;
    __syncthreads();
    for (int off = 128; off; off >>= 1) {
        if (t < off) sd[t] += sd[t + off];
        __syncthreads();
    }
    if (t == 0) {
        atomicAdd(lossAcc, sd[0]);
        __threadfence();
        int done = atomicAdd(ticket, 1);
        if (done == NFINAL - 1) {
            double total = atomicAdd(lossAcc, 0.0);  // RMW read: coherent total
            out[0] = (float)(total / BSZ);
        }
    }
}

extern "C" void kernel_launch(void* const* d_in, const int* in_sizes, int n_in,
                              void* d_out, int out_size, void* d_ws, size_t ws_size,
                              hipStream_t stream) {
    const float* f1    = (const float*)d_in[0];
    const float* f2    = (const float*)d_in[1];
    const int*   label = (const int*)d_in[2];
    float* out = (float*)d_out;

    // ws layout: pos[B], neg[B], Tsum[B] (f32), lossAcc (f64), ticket (i32),
    // pad to 16B, then Ah/Al/Bh/Bl fp16 matrices.
    float* stats = (float*)d_ws;
    float* pos   = stats;
    float* neg   = stats + BSZ;
    float* Tsum  = stats + 2 * BSZ;
    double* lossAcc = (double*)(stats + 3 * BSZ);       // byte 98304, 8-aligned
    int* ticket  = (int*)(stats + 3 * BSZ + 2);
    f16* Ah = (f16*)((char*)d_ws + 3 * BSZ * sizeof(float) + 16);
    f16* Al = Ah + (size_t)BSZ * DDIM;
    f16* Bh = Al + (size_t)BSZ * DDIM;
    f16* Bl = Bh + (size_t)BSZ * DDIM;

    prep_kernel<<<dim3(BSZ / 4, 2), dim3(256), 0, stream>>>(f1, f2, Ah, Al, Bh, Bl, stats);

    gemm_pass_kernel<<<dim3(BSZ / 256, BSZ / 128), dim3(256), 0, stream>>>(
        Ah, Al, Bh, Bl, label, pos, neg, Tsum);

    final_kernel<<<dim3(NFINAL), dim3(256), 0, stream>>>(pos, neg, Tsum, lossAcc, ticket, out);
}